// Round 2
// baseline (432.863 us; speedup 1.0000x reference)
//
#include <hip/hip_runtime.h>

#define IMG_H 256
#define IMG_W 256
#define KS 33
#define PAD 16
#define THRESH 1e-4f
#define ROWS 4                      // image rows per block (1 per wave)
#define LW (IMG_W + 2 * PAD)        // padded row width = 288
#define PLANE (IMG_H * IMG_W)       // 65536
#define PLANE4 (PLANE / 4)          // 16384 float4s per tap plane

__device__ __forceinline__ float f4c(const float4 v, int i) {
    return i == 0 ? v.x : i == 1 ? v.y : i == 2 ? v.z : v.w;
}

// Block = 256 threads = 4 waves; each wave owns one image row, each lane owns
// 4 consecutive pixels (x0 = 4*lane). grid = (64 row-groups, 33 fh values) =
// 2112 blocks = 8448 waves (33/CU) — round-0-level parallelism with round-1's
// vectorized loads. Each block handles ONE fh (33 fw taps): per tap one
// global_load_dwordx4 of Kernels (1 KB per wave-load, stream-once) and
// 16B-aligned LDS sliding windows for the image (staged clamped+padded once,
// 3ch x 4rows x 288 = 13.5 KB). Partials atomicAdd'd into d_out (zeroed first).
__global__ __launch_bounds__(256, 4)
void reblur_kernel(const float* __restrict__ img,
                   const float* __restrict__ ker,
                   float* __restrict__ out)
{
    const int tid   = threadIdx.x;
    const int wvid  = tid >> 6;          // 0..3: row within block
    const int lane  = tid & 63;
    const int ybase = blockIdx.x * ROWS;
    const int y     = ybase + wvid;
    const int fh    = blockIdx.y;        // 0..32
    const int x0    = lane * 4;

    __shared__ __align__(16) float simg[3][ROWS][LW];

    // Stage padded rows: simg[c][r][px] = img[c][clamp(ybase+fh+r-16)][clamp(px-16)]
    const int tot = 3 * ROWS * LW;       // 3456
    for (int i = tid; i < tot; i += 256) {
        const int c  = i / (ROWS * LW);
        const int rm = i - c * (ROWS * LW);
        const int r  = rm / LW;
        const int px = rm - r * LW;
        int yy = ybase + fh + r - PAD;
        yy = yy < 0 ? 0 : (yy > IMG_H - 1 ? IMG_H - 1 : yy);
        int xx = px - PAD;
        xx = xx < 0 ? 0 : (xx > IMG_W - 1 ? IMG_W - 1 : xx);
        simg[c][r][px] = img[c * PLANE + yy * IMG_W + xx];
    }
    __syncthreads();

    float acc[3][4] = {};

    // float4 view of Kernels: tap k = fh*33 + fw, row y, lanes cover the row.
    const float4* kf = reinterpret_cast<const float4*>(ker)
                     + (size_t)fh * KS * PLANE4 + y * (IMG_W / 4) + lane;

    const float4* s0 = reinterpret_cast<const float4*>(&simg[0][wvid][x0]);
    const float4* s1 = reinterpret_cast<const float4*>(&simg[1][wvid][x0]);
    const float4* s2 = reinterpret_cast<const float4*>(&simg[2][wvid][x0]);

    float4 a0 = s0[0], a1 = s1[0], a2 = s2[0];

    #pragma unroll
    for (int g = 0; g < 8; ++g) {        // taps fw = 4g .. 4g+3
        const float4 b0 = s0[g + 1];
        const float4 b1 = s1[g + 1];
        const float4 b2 = s2[g + 1];
        #pragma unroll
        for (int j = 0; j < 4; ++j) {
            const float4 wt = kf[(size_t)(4 * g + j) * PLANE4];
            float4 th;
            th.x = wt.x > THRESH ? wt.x : 0.f;
            th.y = wt.y > THRESH ? wt.y : 0.f;
            th.z = wt.z > THRESH ? wt.z : 0.f;
            th.w = wt.w > THRESH ? wt.w : 0.f;
            #pragma unroll
            for (int p = 0; p < 4; ++p) {
                const int e = j + p;             // window element, 0..6
                const float v0 = e < 4 ? f4c(a0, e) : f4c(b0, e - 4);
                const float v1 = e < 4 ? f4c(a1, e) : f4c(b1, e - 4);
                const float v2 = e < 4 ? f4c(a2, e) : f4c(b2, e - 4);
                const float w  = f4c(th, p);
                acc[0][p] = fmaf(w, v0, acc[0][p]);
                acc[1][p] = fmaf(w, v1, acc[1][p]);
                acc[2][p] = fmaf(w, v2, acc[2][p]);
            }
        }
        a0 = b0; a1 = b1; a2 = b2;
    }

    // tail tap fw = 32: window is a* (== s*[8] = padded cols x0+32 .. x0+35)
    {
        const float4 wt = kf[(size_t)32 * PLANE4];
        float4 th;
        th.x = wt.x > THRESH ? wt.x : 0.f;
        th.y = wt.y > THRESH ? wt.y : 0.f;
        th.z = wt.z > THRESH ? wt.z : 0.f;
        th.w = wt.w > THRESH ? wt.w : 0.f;
        #pragma unroll
        for (int p = 0; p < 4; ++p) {
            const float w = f4c(th, p);
            acc[0][p] = fmaf(w, f4c(a0, p), acc[0][p]);
            acc[1][p] = fmaf(w, f4c(a1, p), acc[1][p]);
            acc[2][p] = fmaf(w, f4c(a2, p), acc[2][p]);
        }
    }

    const int obase = y * IMG_W + x0;
    #pragma unroll
    for (int p = 0; p < 4; ++p) {
        atomicAdd(out + obase + p,             acc[0][p]);
        atomicAdd(out + PLANE + obase + p,     acc[1][p]);
        atomicAdd(out + 2 * PLANE + obase + p, acc[2][p]);
    }
}

extern "C" void kernel_launch(void* const* d_in, const int* in_sizes, int n_in,
                              void* d_out, int out_size, void* d_ws, size_t ws_size,
                              hipStream_t stream) {
    const float* img = (const float*)d_in[0];   // [1,3,256,256] fp32
    const float* ker = (const float*)d_in[1];   // [1,1089,256,256] fp32
    float* out = (float*)d_out;                 // [1,3,256,256] fp32

    // d_out is poisoned 0xAA before every timed launch — zero it ourselves.
    hipMemsetAsync(out, 0, (size_t)out_size * sizeof(float), stream);

    dim3 grid(IMG_H / ROWS, KS);                // (64, 33)
    reblur_kernel<<<grid, 256, 0, stream>>>(img, ker, out);
}

// Round 3
// 381.511 us; speedup vs baseline: 1.1346x; 1.1346x over previous
//
#include <hip/hip_runtime.h>

#define IMG_H 256
#define IMG_W 256
#define IMG_C 3
#define KS 33
#define PAD 16
#define THRESH 1e-4f
#define FH_PER 3   // 33 fh values split into 11 chunks of 3

// One thread per pixel, block = one image row (x = tid, coalesced over Kernels' x).
// grid = (256 rows, 11 fh-chunks). Each chunk accumulates 3*33 = 99 taps, then
// atomicAdd's its 3 channel partials into d_out (zeroed by memset before launch).
//
// Session conclusion: this structure is at the memory roofline. The mandatory
// 285.5 MB Kernels stream at the measured ~6.7 TB/s ceiling is ~42 us; this
// kernel's attributable time is ~38-42 us (dur_us minus the 2x ~172 us harness
// poison fills visible in rocprof). Restructures with float4+LDS (rounds 1-2)
// regressed to ~72-89 us despite fewer VMEM instructions — 99 independent
// 256 B wave-loads at 44 waves/CU already saturate HBM.
__global__ __launch_bounds__(256, 4)
void reblur_kernel(const float* __restrict__ img,
                   const float* __restrict__ ker,
                   float* __restrict__ out)
{
    const int x = threadIdx.x;          // 0..255
    const int y = blockIdx.x;           // 0..255
    const int chunk = blockIdx.y;       // 0..10
    const int fh0 = chunk * FH_PER;

    const int pix = y * IMG_W + x;
    const int plane = IMG_H * IMG_W;

    // Kernels layout: [k][y][x], k = fh*33 + fw
    const float* kp = ker + (size_t)(fh0 * KS) * plane + pix;

    float a0 = 0.f, a1 = 0.f, a2 = 0.f;
    const int xm = x - PAD;

    #pragma unroll
    for (int dfh = 0; dfh < FH_PER; ++dfh) {
        int yy = y + (fh0 + dfh) - PAD;
        yy = yy < 0 ? 0 : (yy > IMG_H - 1 ? IMG_H - 1 : yy);
        const float* __restrict__ r0 = img + yy * IMG_W;            // ch 0 row
        const float* __restrict__ r1 = r0 + plane;                  // ch 1 row
        const float* __restrict__ r2 = r1 + plane;                  // ch 2 row
        #pragma unroll
        for (int fw = 0; fw < KS; ++fw) {
            float w = *kp;
            kp += plane;                 // next tap k -> +65536 floats
            int xx = xm + fw;            // replication clamp
            xx = xx < 0 ? 0 : (xx > IMG_W - 1 ? IMG_W - 1 : xx);
            float we = (w > THRESH) ? w : 0.f;
            a0 = fmaf(we, r0[xx], a0);
            a1 = fmaf(we, r1[xx], a1);
            a2 = fmaf(we, r2[xx], a2);
        }
    }

    atomicAdd(out + pix,             a0);
    atomicAdd(out + plane + pix,     a1);
    atomicAdd(out + 2 * plane + pix, a2);
}

extern "C" void kernel_launch(void* const* d_in, const int* in_sizes, int n_in,
                              void* d_out, int out_size, void* d_ws, size_t ws_size,
                              hipStream_t stream) {
    const float* img = (const float*)d_in[0];   // [1,3,256,256] fp32
    const float* ker = (const float*)d_in[1];   // [1,1089,256,256] fp32
    float* out = (float*)d_out;                 // [1,3,256,256] fp32

    // d_out is poisoned 0xAA before every timed launch — zero it ourselves.
    hipMemsetAsync(out, 0, (size_t)out_size * sizeof(float), stream);

    dim3 grid(IMG_H, (KS + FH_PER - 1) / FH_PER);   // (256, 11)
    reblur_kernel<<<grid, IMG_W, 0, stream>>>(img, ker, out);
}